// Round 2
// baseline (247.688 us; speedup 1.0000x reference)
//
#include <hip/hip_runtime.h>
#include <hip/hip_bf16.h>
#include <math.h>

typedef __bf16 bf16;
typedef bf16 bf16x8 __attribute__((ext_vector_type(8)));
typedef bf16 bf16x4 __attribute__((ext_vector_type(4)));
typedef float f32x4 __attribute__((ext_vector_type(4)));

#define N_NODES 8192
#define DIN 256
#define DOUT 256
#define KCAT 512
#define EPSF 1e-8f

__device__ __forceinline__ f32x4 mfma16(bf16x8 a, bf16x8 b, f32x4 c) {
    return __builtin_amdgcn_mfma_f32_16x16x32_bf16(a, b, c, 0, 0, 0);
}

// ---------------- K0: W_w [256x256] -> WwT[n][k] bf16 ; W_fc [512x256] -> WfcT[n][k] bf16
__global__ __launch_bounds__(256) void k0_prep(const float* __restrict__ Ww,
                                               const float* __restrict__ Wfc,
                                               bf16* __restrict__ WwT,
                                               bf16* __restrict__ WfcT) {
    int tid = blockIdx.x * 256 + threadIdx.x;
    if (tid < 256 * 256) {
        int n = tid >> 8, k = tid & 255;
        WwT[n * 256 + k] = (bf16)Ww[k * 256 + n];
    }
    if (tid < 256 * 512) {
        int n = tid >> 9, k = tid & 511;
        WfcT[n * 512 + k] = (bf16)Wfc[k * 256 + n];
    }
}

// ---------------- K1: hT[col][m] = bf16(relu(X @ W_w + b_w))
__global__ __launch_bounds__(128) void k1_h(const float* __restrict__ X,
                                            const bf16* __restrict__ WwT,
                                            const float* __restrict__ bw,
                                            bf16* __restrict__ hT) {
    const int lane = threadIdx.x & 63;
    const int wid  = threadIdx.x >> 6;   // 0..1
    const int m0   = blockIdx.x * 16;
    const int lrow = lane & 15;
    const int lk8  = (lane >> 4) * 8;

    f32x4 acc[8];
#pragma unroll
    for (int i = 0; i < 8; ++i) acc[i] = {0.f, 0.f, 0.f, 0.f};

#pragma unroll
    for (int ks = 0; ks < DIN; ks += 32) {
        const float* xp = X + (size_t)(m0 + lrow) * DIN + ks + lk8;
        f32x4 x0 = *reinterpret_cast<const f32x4*>(xp);
        f32x4 x1 = *reinterpret_cast<const f32x4*>(xp + 4);
        bf16x8 a;
#pragma unroll
        for (int j = 0; j < 4; ++j) { a[j] = (bf16)x0[j]; a[4 + j] = (bf16)x1[j]; }
#pragma unroll
        for (int nb = 0; nb < 8; ++nb) {
            int col = wid * 128 + nb * 16 + lrow;
            bf16x8 b = *reinterpret_cast<const bf16x8*>(WwT + (size_t)col * DIN + ks + lk8);
            acc[nb] = mfma16(a, b, acc[nb]);
        }
    }
    const int mrow = m0 + (lane >> 4) * 4;
#pragma unroll
    for (int nb = 0; nb < 8; ++nb) {
        int col = wid * 128 + nb * 16 + lrow;
        float bias = bw[col];
        bf16x4 hv;
#pragma unroll
        for (int j = 0; j < 4; ++j) {
            float v = acc[nb][j] + bias;
            hv[j] = (bf16)(v > 0.f ? v : 0.f);
        }
        *reinterpret_cast<bf16x4*>(hT + (size_t)col * N_NODES + mrow) = hv;
    }
}

// ---------------- K2: pooled = (A @ h) / (rowsum(A)+eps), bf16 out
// grid 256 blocks x 512 thr (8 waves). Block = 32 rows x 256 cols, BK=256.
// A: fp32 nontemporal global -> regs (4x f32x4/thread, 1 tile prefetch) ->
//    cvt bf16 -> XOR-swizzled LDS [32][256] dbuf (1 barrier/iter).
// B: direct from hT (L2-resident), exactly once per block.
// rowsum: wave wid handles kki==wid (uniform +2 MFMA/wave), LDS-reduced at end.
__global__ __launch_bounds__(512) void k2_pool(const float* __restrict__ A,
                                               const bf16* __restrict__ hT,
                                               bf16* __restrict__ pooled) {
    __shared__ __align__(16) unsigned char As[2 * 16384];   // 2 x [32 rows][512 B]
    __shared__ float rsPart[8][32];
    __shared__ float rs[32];
    const int t    = threadIdx.x;
    const int lane = t & 63;
    const int wid  = t >> 6;   // 0..7
    const int m0   = blockIdx.x * 32;
    const int lrow = lane & 15;
    const int lk8  = (lane >> 4) * 8;

    f32x4 acc[2][2];
    f32x4 sums[2];
#pragma unroll
    for (int i = 0; i < 2; ++i) {
        sums[i] = {0.f, 0.f, 0.f, 0.f};
#pragma unroll
        for (int j = 0; j < 2; ++j) acc[i][j] = {0.f, 0.f, 0.f, 0.f};
    }
    bf16x8 bOne;
#pragma unroll
    for (int j = 0; j < 8; ++j) bOne[j] = (bf16)1.0f;

    // staging: thread t handles row sr, 16 consecutive floats at col sc16
    const int sr   = t >> 4;           // 0..31
    const int sc16 = (t & 15) * 16;    // 0..240
    const float* aSrc = A + (size_t)(m0 + sr) * N_NODES + sc16;
    const int wxr = (sr & 7) << 4;
    const int wb0 = (sr * 512 + sc16 * 2) ^ wxr;
    const int wb1 = (sr * 512 + sc16 * 2 + 16) ^ wxr;

    // fragment read bases (XOR applied to final addr; kki*64 overlaps bit6)
    int rBase[2], rXr[2];
#pragma unroll
    for (int mf = 0; mf < 2; ++mf) {
        int row = mf * 16 + lrow;
        rBase[mf] = row * 512 + lk8 * 2;
        rXr[mf]   = (row & 7) << 4;
    }

    const bf16* bp0 = hT + (size_t)(wid * 32 + lrow) * N_NODES + lk8;
    const bf16* bp1 = bp0 + (size_t)16 * N_NODES;

    // prologue: load tile 0
    f32x4 ra0 = __builtin_nontemporal_load(reinterpret_cast<const f32x4*>(aSrc + 0));
    f32x4 ra1 = __builtin_nontemporal_load(reinterpret_cast<const f32x4*>(aSrc + 4));
    f32x4 ra2 = __builtin_nontemporal_load(reinterpret_cast<const f32x4*>(aSrc + 8));
    f32x4 ra3 = __builtin_nontemporal_load(reinterpret_cast<const f32x4*>(aSrc + 12));

    const int NT = N_NODES / 256;  // 32
    for (int tile = 0; tile < NT; ++tile) {
        unsigned char* buf = As + (tile & 1) * 16384;
        bf16x8 w0, w1;
#pragma unroll
        for (int j = 0; j < 4; ++j) {
            w0[j] = (bf16)ra0[j]; w0[4 + j] = (bf16)ra1[j];
            w1[j] = (bf16)ra2[j]; w1[4 + j] = (bf16)ra3[j];
        }
        *reinterpret_cast<bf16x8*>(buf + wb0) = w0;
        *reinterpret_cast<bf16x8*>(buf + wb1) = w1;
        if (tile + 1 < NT) {
            const float* p = aSrc + (size_t)(tile + 1) * 256;
            ra0 = __builtin_nontemporal_load(reinterpret_cast<const f32x4*>(p + 0));
            ra1 = __builtin_nontemporal_load(reinterpret_cast<const f32x4*>(p + 4));
            ra2 = __builtin_nontemporal_load(reinterpret_cast<const f32x4*>(p + 8));
            ra3 = __builtin_nontemporal_load(reinterpret_cast<const f32x4*>(p + 12));
        }
        __syncthreads();
        const bf16* bt0 = bp0 + (size_t)tile * 256;
        const bf16* bt1 = bp1 + (size_t)tile * 256;
#pragma unroll
        for (int kki = 0; kki < 8; ++kki) {
            bf16x8 a0 = *reinterpret_cast<const bf16x8*>(buf + ((rBase[0] + kki * 64) ^ rXr[0]));
            bf16x8 a1 = *reinterpret_cast<const bf16x8*>(buf + ((rBase[1] + kki * 64) ^ rXr[1]));
            bf16x8 b0 = *reinterpret_cast<const bf16x8*>(bt0 + kki * 32);
            bf16x8 b1 = *reinterpret_cast<const bf16x8*>(bt1 + kki * 32);
            acc[0][0] = mfma16(a0, b0, acc[0][0]);
            acc[1][0] = mfma16(a1, b0, acc[1][0]);
            acc[0][1] = mfma16(a0, b1, acc[0][1]);
            acc[1][1] = mfma16(a1, b1, acc[1][1]);
            if (wid == kki) {
                sums[0] = mfma16(a0, bOne, sums[0]);
                sums[1] = mfma16(a1, bOne, sums[1]);
            }
        }
        // double-buffered: single barrier per iteration (writes of tile+1 target
        // the other buffer; barrier at t+1 can't be passed until all waves
        // finished compute of tile t, protecting buf reuse at t+2)
    }

    // reduce rowsum partials across the 8 waves
    if (lrow == 0) {
        int rbase = (lane >> 4) * 4;
#pragma unroll
        for (int j = 0; j < 4; ++j) {
            rsPart[wid][rbase + j]      = sums[0][j];
            rsPart[wid][16 + rbase + j] = sums[1][j];
        }
    }
    __syncthreads();
    if (t < 32) {
        float s = 0.f;
#pragma unroll
        for (int w = 0; w < 8; ++w) s += rsPart[w][t];
        rs[t] = s;
    }
    __syncthreads();

#pragma unroll
    for (int mf = 0; mf < 2; ++mf)
#pragma unroll
        for (int nb = 0; nb < 2; ++nb) {
            int col = wid * 32 + nb * 16 + lrow;
#pragma unroll
            for (int j = 0; j < 4; ++j) {
                int row = mf * 16 + (lane >> 4) * 4 + j;
                float v = acc[mf][nb][j] / (rs[row] + EPSF);
                pooled[(size_t)(m0 + row) * DOUT + col] = (bf16)v;
            }
        }
}

// ---------------- K3: out = relu([X || pooled] @ W_fc + b_fc) + eps, + per-block sumsq partial
__global__ __launch_bounds__(128) void k3_out(const float* __restrict__ X,
                                              const bf16* __restrict__ pooled,
                                              const bf16* __restrict__ WfcT,
                                              const float* __restrict__ bfc,
                                              float* __restrict__ out,
                                              float* __restrict__ partials) {
    const int lane = threadIdx.x & 63;
    const int wid  = threadIdx.x >> 6;
    const int m0   = blockIdx.x * 16;
    const int lrow = lane & 15;
    const int lk8  = (lane >> 4) * 8;

    f32x4 acc[8];
#pragma unroll
    for (int i = 0; i < 8; ++i) acc[i] = {0.f, 0.f, 0.f, 0.f};

#pragma unroll
    for (int ks = 0; ks < 256; ks += 32) {
        const float* xp = X + (size_t)(m0 + lrow) * DIN + ks + lk8;
        f32x4 x0 = *reinterpret_cast<const f32x4*>(xp);
        f32x4 x1 = *reinterpret_cast<const f32x4*>(xp + 4);
        bf16x8 a;
#pragma unroll
        for (int j = 0; j < 4; ++j) { a[j] = (bf16)x0[j]; a[4 + j] = (bf16)x1[j]; }
#pragma unroll
        for (int nb = 0; nb < 8; ++nb) {
            int col = wid * 128 + nb * 16 + lrow;
            bf16x8 b = *reinterpret_cast<const bf16x8*>(WfcT + (size_t)col * KCAT + ks + lk8);
            acc[nb] = mfma16(a, b, acc[nb]);
        }
    }
#pragma unroll
    for (int ks = 256; ks < 512; ks += 32) {
        bf16x8 a = *reinterpret_cast<const bf16x8*>(pooled + (size_t)(m0 + lrow) * DOUT + (ks - 256) + lk8);
#pragma unroll
        for (int nb = 0; nb < 8; ++nb) {
            int col = wid * 128 + nb * 16 + lrow;
            bf16x8 b = *reinterpret_cast<const bf16x8*>(WfcT + (size_t)col * KCAT + ks + lk8);
            acc[nb] = mfma16(a, b, acc[nb]);
        }
    }

    float ss = 0.f;
#pragma unroll
    for (int nb = 0; nb < 8; ++nb) {
        int col = wid * 128 + nb * 16 + lrow;
        float bias = bfc[col];
#pragma unroll
        for (int j = 0; j < 4; ++j) {
            int row = m0 + (lane >> 4) * 4 + j;
            float v = acc[nb][j] + bias;
            v = (v > 0.f ? v : 0.f) + EPSF;
            out[(size_t)row * DOUT + col] = v;
            ss += v * v;
        }
    }
#pragma unroll
    for (int off = 32; off; off >>= 1) ss += __shfl_xor(ss, off);
    __shared__ float sw[2];
    if (lane == 0) sw[wid] = ss;
    __syncthreads();
    if (threadIdx.x == 0) partials[blockIdx.x] = sw[0] + sw[1];
}

// ---------------- K4: deterministic reduce of 512 partials; scale out by 1/(norm+eps)
__global__ __launch_bounds__(256) void k4_norm(float* __restrict__ out,
                                               const float* __restrict__ partials) {
    __shared__ float sw[4];
    float s = partials[threadIdx.x] + partials[threadIdx.x + 256];
#pragma unroll
    for (int off = 32; off; off >>= 1) s += __shfl_xor(s, off);
    if ((threadIdx.x & 63) == 0) sw[threadIdx.x >> 6] = s;
    __syncthreads();
    float total = sw[0] + sw[1] + sw[2] + sw[3];
    float scale = 1.f / (sqrtf(total) + EPSF);
    f32x4* o4 = reinterpret_cast<f32x4*>(out);
    const int nvec = N_NODES * DOUT / 4;
    for (int i = blockIdx.x * blockDim.x + threadIdx.x; i < nvec; i += gridDim.x * blockDim.x) {
        f32x4 v = o4[i];
#pragma unroll
        for (int j = 0; j < 4; ++j) v[j] *= scale;
        o4[i] = v;
    }
}

extern "C" void kernel_launch(void* const* d_in, const int* in_sizes, int n_in,
                              void* d_out, int out_size, void* d_ws, size_t ws_size,
                              hipStream_t stream) {
    const float* A   = (const float*)d_in[0];
    const float* X   = (const float*)d_in[1];
    const float* Ww  = (const float*)d_in[2];
    const float* bw  = (const float*)d_in[3];
    const float* Wfc = (const float*)d_in[4];
    const float* bfc = (const float*)d_in[5];
    float* out = (float*)d_out;

    char* ws = (char*)d_ws;
    bf16*  hT       = (bf16*)(ws);                                  // 4 MiB
    bf16*  pooled   = (bf16*)(ws + (4u << 20));                     // 4 MiB
    bf16*  WwT      = (bf16*)(ws + (8u << 20));                     // 128 KiB
    bf16*  WfcT     = (bf16*)(ws + (8u << 20) + (128u << 10));      // 256 KiB
    float* partials = (float*)(ws + (8u << 20) + (384u << 10));     // 2 KiB

    k0_prep<<<512, 256, 0, stream>>>(Ww, Wfc, WwT, WfcT);
    k1_h<<<512, 128, 0, stream>>>(X, WwT, bw, hT);
    k2_pool<<<256, 512, 0, stream>>>(A, hT, pooled);
    k3_out<<<512, 128, 0, stream>>>(X, pooled, WfcT, bfc, out, partials);
    k4_norm<<<256, 256, 0, stream>>>(out, partials);
}

// Round 3
// 137.957 us; speedup vs baseline: 1.7954x; 1.7954x over previous
//
#include <hip/hip_runtime.h>
#include <hip/hip_bf16.h>
#include <math.h>

typedef __bf16 bf16;
typedef bf16 bf16x8 __attribute__((ext_vector_type(8)));
typedef bf16 bf16x4 __attribute__((ext_vector_type(4)));
typedef float f32x4 __attribute__((ext_vector_type(4)));

#define N_NODES 8192
#define DIN 256
#define DOUT 256
#define KCAT 512
#define EPSF 1e-8f
#define KSPLIT 4
#define KBLK 2048          // K per block = N_NODES / KSPLIT
#define BM 128
#define BK 64
#define NT (KBLK / BK)     // 32 tiles
#define BUFSZ 49152        // A 16 KB + B 32 KB

__device__ __forceinline__ f32x4 mfma16(bf16x8 a, bf16x8 b, f32x4 c) {
    return __builtin_amdgcn_mfma_f32_16x16x32_bf16(a, b, c, 0, 0, 0);
}

#define WAITVM(N) asm volatile("s_waitcnt vmcnt(" #N ")" ::: "memory")
#define WAITLGKM  asm volatile("s_waitcnt lgkmcnt(0)" ::: "memory")
#define BAR       __builtin_amdgcn_s_barrier()

// ---------------- K0: W_w [256x256] -> WwT[n][k] bf16 ; W_fc [512x256] -> WfcT[n][k] bf16
__global__ __launch_bounds__(256) void k0_prep(const float* __restrict__ Ww,
                                               const float* __restrict__ Wfc,
                                               bf16* __restrict__ WwT,
                                               bf16* __restrict__ WfcT) {
    int tid = blockIdx.x * 256 + threadIdx.x;
    if (tid < 256 * 256) {
        int n = tid >> 8, k = tid & 255;
        WwT[n * 256 + k] = (bf16)Ww[k * 256 + n];
    }
    if (tid < 256 * 512) {
        int n = tid >> 9, k = tid & 511;
        WfcT[n * 512 + k] = (bf16)Wfc[k * 256 + n];
    }
}

// ---------------- K1: hT[col][m] = bf16(relu(X @ W_w + b_w))
__global__ __launch_bounds__(128) void k1_h(const float* __restrict__ X,
                                            const bf16* __restrict__ WwT,
                                            const float* __restrict__ bw,
                                            bf16* __restrict__ hT) {
    const int lane = threadIdx.x & 63;
    const int wid  = threadIdx.x >> 6;   // 0..1
    const int m0   = blockIdx.x * 16;
    const int lrow = lane & 15;
    const int lk8  = (lane >> 4) * 8;

    f32x4 acc[8];
#pragma unroll
    for (int i = 0; i < 8; ++i) acc[i] = {0.f, 0.f, 0.f, 0.f};

#pragma unroll
    for (int ks = 0; ks < DIN; ks += 32) {
        const float* xp = X + (size_t)(m0 + lrow) * DIN + ks + lk8;
        f32x4 x0 = *reinterpret_cast<const f32x4*>(xp);
        f32x4 x1 = *reinterpret_cast<const f32x4*>(xp + 4);
        bf16x8 a;
#pragma unroll
        for (int j = 0; j < 4; ++j) { a[j] = (bf16)x0[j]; a[4 + j] = (bf16)x1[j]; }
#pragma unroll
        for (int nb = 0; nb < 8; ++nb) {
            int col = wid * 128 + nb * 16 + lrow;
            bf16x8 b = *reinterpret_cast<const bf16x8*>(WwT + (size_t)col * DIN + ks + lk8);
            acc[nb] = mfma16(a, b, acc[nb]);
        }
    }
    const int mrow = m0 + (lane >> 4) * 4;
#pragma unroll
    for (int nb = 0; nb < 8; ++nb) {
        int col = wid * 128 + nb * 16 + lrow;
        float bias = bw[col];
        bf16x4 hv;
#pragma unroll
        for (int j = 0; j < 4; ++j) {
            float v = acc[nb][j] + bias;
            hv[j] = (bf16)(v > 0.f ? v : 0.f);
        }
        *reinterpret_cast<bf16x4*>(hT + (size_t)col * N_NODES + mrow) = hv;
    }
}

// ---------------- K2: partial pooled = A[m0:m0+128, kbase:kbase+2048] @ h[k-range]
// grid 256 = 64 M-blocks x 4 K-splits, 512 thr (8 waves as 2x4 of 64x64 tiles).
// A: coalesced f32x4 loads -> cvt bf16 -> XOR-swizzled ds_write (16 KB/tile).
// B: global_load_lds 16B/lane, source-pre-swizzled, linear LDS dest (32 KB/tile).
// 2-phase counted-vmcnt pipeline, raw s_barrier (no vmcnt(0) drain in loop).
// rowsum partial: waves wn==kki do an extra MFMA with all-ones B.
__global__ __launch_bounds__(512) void k2_pool(const float* __restrict__ A,
                                               const bf16* __restrict__ hT,
                                               float* __restrict__ part,
                                               float* __restrict__ rsG) {
    __shared__ __align__(16) unsigned char lds[2][BUFSZ];
    __shared__ float rsp[2][BM];
    const int t    = threadIdx.x;
    const int lane = t & 63;
    const int wid  = t >> 6;        // 0..7
    const int wr   = wid >> 2;      // 0..1  (row half)
    const int wn   = wid & 3;       // 0..3  (col quarter)
    const int lrow = lane & 15;
    const int lk4  = lane >> 4;     // 0..3
    const int mblk = blockIdx.x & 63;
    const int ks   = blockIdx.x >> 6;
    const int m0   = mblk * BM;
    const int kbase = ks * KBLK;

    f32x4 acc[4][4];
    f32x4 sums[4];
#pragma unroll
    for (int i = 0; i < 4; ++i) {
        sums[i] = {0.f, 0.f, 0.f, 0.f};
#pragma unroll
        for (int j = 0; j < 4; ++j) acc[i][j] = {0.f, 0.f, 0.f, 0.f};
    }
    bf16x8 bOne;
#pragma unroll
    for (int j = 0; j < 8; ++j) bOne[j] = (bf16)1.0f;

    // ---- A staging assignment: thread t -> row t>>2, 16 floats at (t&3)*16
    const int arow = t >> 2;
    const int aq   = t & 3;
    const float* aSrc = A + (size_t)(m0 + arow) * N_NODES + kbase + aq * 16;
    const int awb0 = arow * 128 + (((aq * 2)     ^ (arow & 7)) << 4);
    const int awb1 = arow * 128 + (((aq * 2 + 1) ^ (arow & 7)) << 4);

    // ---- B DMA assignment (4 rounds): idx = r*512+t -> col=idx>>3, seg=(idx&7)^(col&7)
    int bcol[4], bseg[4], bldsoff[4];
#pragma unroll
    for (int r = 0; r < 4; ++r) {
        int idx = r * 512 + t;
        bcol[r] = idx >> 3;
        bseg[r] = (idx & 7) ^ (bcol[r] & 7);
        bldsoff[r] = 16384 + (r * 8 + wid) * 1024;   // wave-uniform base within buffer
    }

    // ---- fragment read byte offsets
    int aOff[2][4], bOff[2][4];
#pragma unroll
    for (int kki = 0; kki < 2; ++kki) {
        int sA = kki * 4 + lk4;
#pragma unroll
        for (int f = 0; f < 4; ++f) {
            int row = wr * 64 + f * 16 + lrow;
            aOff[kki][f] = row * 128 + ((sA ^ (row & 7)) << 4);
            int col = wn * 64 + f * 16 + lrow;
            bOff[kki][f] = 16384 + col * 128 + ((sA ^ (col & 7)) << 4);
        }
    }

    f32x4 ra0, ra1, ra2, ra3;

#define ALOAD(tile) do {                                                      \
        const float* p_ = aSrc + (size_t)(tile) * BK;                         \
        ra0 = *reinterpret_cast<const f32x4*>(p_);                            \
        ra1 = *reinterpret_cast<const f32x4*>(p_ + 4);                        \
        ra2 = *reinterpret_cast<const f32x4*>(p_ + 8);                        \
        ra3 = *reinterpret_cast<const f32x4*>(p_ + 12);                       \
    } while (0)

#define CVTWRITE(bufidx) do {                                                 \
        bf16x8 w0_, w1_;                                                      \
        _Pragma("unroll")                                                     \
        for (int j = 0; j < 4; ++j) {                                         \
            w0_[j] = (bf16)ra0[j]; w0_[4 + j] = (bf16)ra1[j];                 \
            w1_[j] = (bf16)ra2[j]; w1_[4 + j] = (bf16)ra3[j];                 \
        }                                                                     \
        *reinterpret_cast<bf16x8*>(&lds[bufidx][awb0]) = w0_;                 \
        *reinterpret_cast<bf16x8*>(&lds[bufidx][awb1]) = w1_;                 \
    } while (0)

#define BDMA(tile, bufidx) do {                                               \
        _Pragma("unroll")                                                     \
        for (int r_ = 0; r_ < 4; ++r_) {                                      \
            const bf16* g_ = hT + (size_t)bcol[r_] * N_NODES + kbase          \
                             + (tile) * BK + bseg[r_] * 8;                    \
            __builtin_amdgcn_global_load_lds(                                 \
                (const __attribute__((address_space(1))) void*)g_,            \
                (__attribute__((address_space(3))) void*)&lds[bufidx][bldsoff[r_]], \
                16, 0, 0);                                                    \
        }                                                                     \
    } while (0)

#define COMPUTE(bufidx) do {                                                  \
        _Pragma("unroll")                                                     \
        for (int kki = 0; kki < 2; ++kki) {                                   \
            bf16x8 af_[4], bf_[4];                                            \
            _Pragma("unroll")                                                 \
            for (int f = 0; f < 4; ++f) {                                     \
                af_[f] = *reinterpret_cast<const bf16x8*>(&lds[bufidx][aOff[kki][f]]); \
                bf_[f] = *reinterpret_cast<const bf16x8*>(&lds[bufidx][bOff[kki][f]]); \
            }                                                                 \
            _Pragma("unroll")                                                 \
            for (int mf = 0; mf < 4; ++mf)                                    \
                _Pragma("unroll")                                             \
                for (int nf = 0; nf < 4; ++nf)                                \
                    acc[mf][nf] = mfma16(af_[mf], bf_[nf], acc[mf][nf]);      \
            if (wn == kki) {                                                  \
                _Pragma("unroll")                                             \
                for (int mf = 0; mf < 4; ++mf)                                \
                    sums[mf] = mfma16(af_[mf], bOne, sums[mf]);               \
            }                                                                 \
        }                                                                     \
    } while (0)

    // ---------------- prologue
    ALOAD(0); BDMA(0, 0);
    CVTWRITE(0);                 // compiler inserts precise vmcnt for ra use
    ALOAD(1); BDMA(1, 1);
    WAITVM(8);                   // B(0) done; A(1)+B(1) (8 newest) may remain
    WAITLGKM;
    BAR;                         // tile 0 ready for all waves

    // ---------------- main loop: tiles 0 .. NT-3
    for (int tt = 0; tt < NT - 2; ++tt) {
        CVTWRITE((tt + 1) & 1);  // A(tt+1) regs -> LDS (compiler waits vmcnt(4))
        COMPUTE(tt & 1);
        ALOAD(tt + 2);
        WAITVM(4);               // B(tt+1) done; A(tt+2) (4 newest) in flight
        WAITLGKM;
        BAR;                     // tile tt+1 ready; all waves done reading buf[tt&1]
        BDMA(tt + 2, tt & 1);
    }
    // ---------------- tail: tiles NT-2, NT-1
    CVTWRITE((NT - 1) & 1);
    COMPUTE((NT - 2) & 1);
    WAITVM(0);                   // drain B(NT-1)
    WAITLGKM;
    BAR;
    COMPUTE((NT - 1) & 1);

    // ---------------- rowsum reduce (waves wn==0/1 hold kki 0/1 partials)
    if (wn < 2 && lrow == 0) {
#pragma unroll
        for (int mf = 0; mf < 4; ++mf)
#pragma unroll
            for (int j = 0; j < 4; ++j)
                rsp[wn][wr * 64 + mf * 16 + lk4 * 4 + j] = sums[mf][j];
    }
    __syncthreads();
    if (t < BM) rsG[(size_t)ks * N_NODES + m0 + t] = rsp[0][t] + rsp[1][t];

    // ---------------- store f32 partial tile
    float* pp = part + ((size_t)ks * N_NODES + m0) * DOUT;
#pragma unroll
    for (int mf = 0; mf < 4; ++mf)
#pragma unroll
        for (int nf = 0; nf < 4; ++nf) {
            int col = wn * 64 + nf * 16 + lrow;
#pragma unroll
            for (int j = 0; j < 4; ++j) {
                int row = wr * 64 + mf * 16 + lk4 * 4 + j;
                pp[(size_t)row * DOUT + col] = acc[mf][nf][j];
            }
        }
#undef ALOAD
#undef CVTWRITE
#undef BDMA
#undef COMPUTE
}

// ---------------- K2b: pooled = (sum_ks part) / (sum_ks rs + eps), bf16
__global__ __launch_bounds__(256) void k2b_combine(const float* __restrict__ part,
                                                   const float* __restrict__ rsG,
                                                   bf16* __restrict__ pooled) {
    int fl  = blockIdx.x * 256 + threadIdx.x;   // one f32x4 (4 cols) per thread
    int row = fl >> 6;
    int c4  = (fl & 63) * 4;
    f32x4 s = {0.f, 0.f, 0.f, 0.f};
#pragma unroll
    for (int ks = 0; ks < KSPLIT; ++ks) {
        f32x4 v = *reinterpret_cast<const f32x4*>(part + ((size_t)ks * N_NODES + row) * DOUT + c4);
#pragma unroll
        for (int j = 0; j < 4; ++j) s[j] += v[j];
    }
    float rs = EPSF;
#pragma unroll
    for (int ks = 0; ks < KSPLIT; ++ks) rs += rsG[(size_t)ks * N_NODES + row];
    float inv = 1.f / rs;
    bf16x4 o;
#pragma unroll
    for (int j = 0; j < 4; ++j) o[j] = (bf16)(s[j] * inv);
    *reinterpret_cast<bf16x4*>(pooled + (size_t)row * DOUT + c4) = o;
}

// ---------------- K3: out = relu([X || pooled] @ W_fc + b_fc) + eps, + per-block sumsq partial
__global__ __launch_bounds__(128) void k3_out(const float* __restrict__ X,
                                              const bf16* __restrict__ pooled,
                                              const bf16* __restrict__ WfcT,
                                              const float* __restrict__ bfc,
                                              float* __restrict__ out,
                                              float* __restrict__ partials) {
    const int lane = threadIdx.x & 63;
    const int wid  = threadIdx.x >> 6;
    const int m0   = blockIdx.x * 16;
    const int lrow = lane & 15;
    const int lk8  = (lane >> 4) * 8;

    f32x4 acc[8];
#pragma unroll
    for (int i = 0; i < 8; ++i) acc[i] = {0.f, 0.f, 0.f, 0.f};

#pragma unroll
    for (int ks = 0; ks < 256; ks += 32) {
        const float* xp = X + (size_t)(m0 + lrow) * DIN + ks + lk8;
        f32x4 x0 = *reinterpret_cast<const f32x4*>(xp);
        f32x4 x1 = *reinterpret_cast<const f32x4*>(xp + 4);
        bf16x8 a;
#pragma unroll
        for (int j = 0; j < 4; ++j) { a[j] = (bf16)x0[j]; a[4 + j] = (bf16)x1[j]; }
#pragma unroll
        for (int nb = 0; nb < 8; ++nb) {
            int col = wid * 128 + nb * 16 + lrow;
            bf16x8 b = *reinterpret_cast<const bf16x8*>(WfcT + (size_t)col * KCAT + ks + lk8);
            acc[nb] = mfma16(a, b, acc[nb]);
        }
    }
#pragma unroll
    for (int ks = 256; ks < 512; ks += 32) {
        bf16x8 a = *reinterpret_cast<const bf16x8*>(pooled + (size_t)(m0 + lrow) * DOUT + (ks - 256) + lk8);
#pragma unroll
        for (int nb = 0; nb < 8; ++nb) {
            int col = wid * 128 + nb * 16 + lrow;
            bf16x8 b = *reinterpret_cast<const bf16x8*>(WfcT + (size_t)col * KCAT + ks + lk8);
            acc[nb] = mfma16(a, b, acc[nb]);
        }
    }

    float ss = 0.f;
#pragma unroll
    for (int nb = 0; nb < 8; ++nb) {
        int col = wid * 128 + nb * 16 + lrow;
        float bias = bfc[col];
#pragma unroll
        for (int j = 0; j < 4; ++j) {
            int row = m0 + (lane >> 4) * 4 + j;
            float v = acc[nb][j] + bias;
            v = (v > 0.f ? v : 0.f) + EPSF;
            out[(size_t)row * DOUT + col] = v;
            ss += v * v;
        }
    }
#pragma unroll
    for (int off = 32; off; off >>= 1) ss += __shfl_xor(ss, off);
    __shared__ float sw[2];
    if (lane == 0) sw[wid] = ss;
    __syncthreads();
    if (threadIdx.x == 0) partials[blockIdx.x] = sw[0] + sw[1];
}

// ---------------- K4: deterministic reduce of 512 partials; scale out by 1/(norm+eps)
__global__ __launch_bounds__(256) void k4_norm(float* __restrict__ out,
                                               const float* __restrict__ partials) {
    __shared__ float sw[4];
    float s = partials[threadIdx.x] + partials[threadIdx.x + 256];
#pragma unroll
    for (int off = 32; off; off >>= 1) s += __shfl_xor(s, off);
    if ((threadIdx.x & 63) == 0) sw[threadIdx.x >> 6] = s;
    __syncthreads();
    float total = sw[0] + sw[1] + sw[2] + sw[3];
    float scale = 1.f / (sqrtf(total) + EPSF);
    f32x4* o4 = reinterpret_cast<f32x4*>(out);
    const int nvec = N_NODES * DOUT / 4;
    for (int i = blockIdx.x * blockDim.x + threadIdx.x; i < nvec; i += gridDim.x * blockDim.x) {
        f32x4 v = o4[i];
#pragma unroll
        for (int j = 0; j < 4; ++j) v[j] *= scale;
        o4[i] = v;
    }
}

extern "C" void kernel_launch(void* const* d_in, const int* in_sizes, int n_in,
                              void* d_out, int out_size, void* d_ws, size_t ws_size,
                              hipStream_t stream) {
    const float* A   = (const float*)d_in[0];
    const float* X   = (const float*)d_in[1];
    const float* Ww  = (const float*)d_in[2];
    const float* bw  = (const float*)d_in[3];
    const float* Wfc = (const float*)d_in[4];
    const float* bfc = (const float*)d_in[5];
    float* out = (float*)d_out;

    char* ws = (char*)d_ws;
    bf16*  hT        = (bf16*)(ws);                                  // 4 MiB
    bf16*  pooled    = (bf16*)(ws + (4u << 20));                     // 4 MiB
    bf16*  WwT       = (bf16*)(ws + (8u << 20));                     // 128 KiB
    bf16*  WfcT      = (bf16*)(ws + (8u << 20) + (128u << 10));      // 256 KiB
    float* partials  = (float*)(ws + (8u << 20) + (384u << 10));     // 2 KiB
    float* rsG       = (float*)(ws + (8u << 20) + (512u << 10));     // 128 KiB
    float* part      = (float*)(ws + (16u << 20));                   // 32 MiB

    k0_prep<<<512, 256, 0, stream>>>(Ww, Wfc, WwT, WfcT);
    k1_h<<<512, 128, 0, stream>>>(X, WwT, bw, hT);
    k2_pool<<<256, 512, 0, stream>>>(A, hT, part, rsG);
    k2b_combine<<<N_NODES * DOUT / 1024, 256, 0, stream>>>(part, rsG, pooled);
    k3_out<<<512, 128, 0, stream>>>(X, pooled, WfcT, bfc, out, partials);
    k4_norm<<<256, 256, 0, stream>>>(out, partials);
}